// Round 3
// baseline (102.197 us; speedup 1.0000x reference)
//
#include <hip/hip_runtime.h>
#include <hip/hip_bf16.h>

// ToneMappingCurveLoss: luma-binned mean-difference loss.
// Inputs: pred, target, input_img: [16, 3, 512, 512] f32. Output: 1 f32 scalar.
// HW = 512*512 = 262144 = 2^18 ; float4 groups per channel = 65536 = 2^16.

#define CH4 65536         // HW/4
#define NBINS 16
#define NCOL (3 * NBINS)  // 48 columns: count, psum, tsum per bin
#define COPIES 64         // per-lane privatized histogram copies

__device__ __forceinline__ float luma_exact(float r, float g, float b) {
    // match numpy/jax f32 evaluation order, no FMA contraction
    return __fadd_rn(__fadd_rn(__fmul_rn(0.299f, r), __fmul_rn(0.587f, g)),
                     __fmul_rn(0.114f, b));
}

__device__ __forceinline__ void process_group(
    const float4& i0, const float4& i1, const float4& i2,
    const float4& p0, const float4& p1, const float4& p2,
    const float4& t0, const float4& t1, const float4& t2,
    float* h, int lane)
{
    const float ir[4] = {i0.x, i0.y, i0.z, i0.w};
    const float ig[4] = {i1.x, i1.y, i1.z, i1.w};
    const float ib[4] = {i2.x, i2.y, i2.z, i2.w};
    const float pr[4] = {p0.x, p0.y, p0.z, p0.w};
    const float pg[4] = {p1.x, p1.y, p1.z, p1.w};
    const float pb[4] = {p2.x, p2.y, p2.z, p2.w};
    const float tr[4] = {t0.x, t0.y, t0.z, t0.w};
    const float tg[4] = {t1.x, t1.y, t1.z, t1.w};
    const float tb[4] = {t2.x, t2.y, t2.z, t2.w};

    #pragma unroll
    for (int j = 0; j < 4; ++j) {
        const float il = luma_exact(ir[j], ig[j], ib[j]);
        if (il < 1.0f) {
            int bin = (int)floorf(__fmul_rn(il, 16.0f));
            bin = min(max(bin, 0), NBINS - 1);
            const float pl = luma_exact(pr[j], pg[j], pb[j]);
            const float tl = luma_exact(tr[j], tg[j], tb[j]);
            atomicAdd(&h[bin * COPIES + lane], 1.0f);
            atomicAdd(&h[(NBINS + bin) * COPIES + lane], pl);
            atomicAdd(&h[(2 * NBINS + bin) * COPIES + lane], tl);
        }
    }
}

__global__ __launch_bounds__(256) void tm_stage1(
    const float4* __restrict__ pred,
    const float4* __restrict__ target,
    const float4* __restrict__ input,
    float* __restrict__ partials,   // column-major [NCOL][rows]
    int G, int rows)
{
    __shared__ float h[NCOL * COPIES];   // 12 KB, per-lane copies
    const int t = threadIdx.x;
    const int lane = t & 63;

    for (int i = t; i < NCOL * COPIES; i += 256) h[i] = 0.0f;
    __syncthreads();

    // Each outer iteration: this block covers 512 consecutive float4-groups;
    // thread t handles groups base+t and base+t+256, both fully unrolled so
    // all 18 loads are in flight before the first use (one vmcnt drain).
    const long long stride = (long long)gridDim.x * 512;
    for (long long base = (long long)blockIdx.x * 512; base < G; base += stride) {
        const int g0 = (int)base + t;
        const int g1 = g0 + 256;
        const bool ok0 = g0 < G;
        const bool ok1 = g1 < G;

        const int b0 = g0 >> 16, q0 = g0 & (CH4 - 1);
        const int b1 = g1 >> 16, q1 = g1 & (CH4 - 1);
        const int a0 = ok0 ? (b0 * (3 * CH4) + q0) : 0;
        const int a1 = ok1 ? (b1 * (3 * CH4) + q1) : 0;

        // issue all 18 loads back-to-back
        const float4 i00 = input[a0];
        const float4 i01 = input[a0 + CH4];
        const float4 i02 = input[a0 + 2 * CH4];
        const float4 p00 = pred[a0];
        const float4 p01 = pred[a0 + CH4];
        const float4 p02 = pred[a0 + 2 * CH4];
        const float4 t00 = target[a0];
        const float4 t01 = target[a0 + CH4];
        const float4 t02 = target[a0 + 2 * CH4];
        const float4 i10 = input[a1];
        const float4 i11 = input[a1 + CH4];
        const float4 i12 = input[a1 + 2 * CH4];
        const float4 p10 = pred[a1];
        const float4 p11 = pred[a1 + CH4];
        const float4 p12 = pred[a1 + 2 * CH4];
        const float4 t10 = target[a1];
        const float4 t11 = target[a1 + CH4];
        const float4 t12 = target[a1 + 2 * CH4];

        if (ok0) process_group(i00, i01, i02, p00, p01, p02, t00, t01, t02, h, lane);
        if (ok1) process_group(i10, i11, i12, p10, p11, p12, t10, t11, t12, h, lane);
    }

    __syncthreads();
    // Block epilogue: 4 waves each reduce 12 columns over the 64 lane-copies.
    const int w = t >> 6;
    #pragma unroll
    for (int k = 0; k < 12; ++k) {
        const int c = w * 12 + k;
        float v = h[c * COPIES + lane];
        v += __shfl_down(v, 32);
        v += __shfl_down(v, 16);
        v += __shfl_down(v, 8);
        v += __shfl_down(v, 4);
        v += __shfl_down(v, 2);
        v += __shfl_down(v, 1);
        if (lane == 0) partials[c * rows + blockIdx.x] = v;
    }
}

__global__ __launch_bounds__(768) void tm_stage2(
    const float4* __restrict__ partials4,  // column-major [NCOL][rows/4] float4
    float* __restrict__ out, int rows4)
{
    __shared__ double col[NCOL];
    const int t = threadIdx.x;          // 768 = 48 cols x 16 threads
    const int c = t >> 4;
    const int l = t & 15;

    double s = 0.0;
    for (int k = l; k < rows4; k += 16) {
        const float4 v = partials4[c * rows4 + k];
        s += (double)v.x + (double)v.y + (double)v.z + (double)v.w;
    }
    #pragma unroll
    for (int k = 8; k; k >>= 1) s += __shfl_down(s, k, 16);
    if (l == 0) col[c] = s;
    __syncthreads();

    if (t == 0) {
        double acc = 0.0;
        #pragma unroll
        for (int i = 0; i < NBINS; ++i) {
            const double cnt = col[i];
            if (cnt > 0.0) {
                acc += fabs(col[NBINS + i] / cnt - col[2 * NBINS + i] / cnt);
            }
        }
        out[0] = (float)(acc / (double)NBINS);
    }
}

extern "C" void kernel_launch(void* const* d_in, const int* in_sizes, int n_in,
                              void* d_out, int out_size, void* d_ws, size_t ws_size,
                              hipStream_t stream) {
    const float* pred   = (const float*)d_in[0];
    const float* target = (const float*)d_in[1];
    const float* input  = (const float*)d_in[2];

    // in_sizes[0] = B*3*H*W ; pixel float4-groups = size / (3*4)
    const int G = in_sizes[0] / 12;

    // One block per 512 groups (2 groups/thread) -> 2048 blocks at this shape
    // (8 blocks/CU). Clamp to workspace capacity; grid-stride loop covers rest.
    int blocks = (G + 511) / 512;
    const size_t maxRows = ws_size / (NCOL * sizeof(float));
    if ((size_t)blocks > maxRows) blocks = (int)maxRows;
    if (blocks < 1) blocks = 1;
    const int rows = (blocks + 3) & ~3;   // pad to multiple of 4 for float4 stage2

    tm_stage1<<<blocks, 256, 0, stream>>>(
        (const float4*)pred, (const float4*)target, (const float4*)input,
        (float*)d_ws, G, rows);
    tm_stage2<<<1, 768, 0, stream>>>((const float4*)d_ws, (float*)d_out, rows / 4);
}